// Round 6
// baseline (4842.887 us; speedup 1.0000x reference)
//
#include <hip/hip_runtime.h>

typedef _Float16 half8 __attribute__((ext_vector_type(8)));
typedef float floatx4 __attribute__((ext_vector_type(4)));
typedef unsigned short ushort_t;

#define D 64
#define SSEG 120
#define NSTEP 600
#define NROW 601
#define BATCH 512

#define CVT16(v) __builtin_bit_cast(ushort_t, (_Float16)(v))

static __device__ __forceinline__ floatx4 mfma16(half8 a, half8 b, floatx4 c) {
  return __builtin_amdgcn_mfma_f32_16x16x32_f16(a, b, c, 0, 0, 0);
}

// Compiler-level memory fence (0 instructions): keeps TBAA from reordering
// aliasing LDS accesses (ushort_t stores vs half8 loads) now that no barrier
// memory-clobbers exist in the single-wave loop.
static __device__ __forceinline__ void cfence() { asm volatile("" ::: "memory"); }

// One block = one WAVE = one trajectory. 512 blocks x 64 threads -> 2 waves/CU
// on separate SIMDs. Whole MLP is VGPR-resident per wave (~420 VGPRs), so the
// step loop has ZERO barriers; layer exchanges are in-wave LDS round-trips
// (LDS is in-order per wave, lgkmcnt auto-tracked by the compiler).
//
// MFMA mapping (R5-verified, M=1 dup rows): A-frag lane(c,kg) = x[ks*32+kg*8..+8]
// broadcast; B-frag = W[n=16t+c][same k]; C col=lane&15, rows duplicated so
// reg 0 is valid in every lane. L3's k lands as k[16t+c] in acc_t -> lane l
// selects t=l>>4 to get k[l]: state element = lane index, no exchange.
extern "C" __global__ void __launch_bounds__(64, 1)
NeuralDDEWithTime_46823733461186_kernel(
    const float* __restrict__ gts, const float* __restrict__ gy0,
    const float* __restrict__ gW1, const float* __restrict__ gb1,
    const float* __restrict__ gW2, const float* __restrict__ gb2,
    const float* __restrict__ gW3, const float* __restrict__ gb3,
    float* __restrict__ gout) {
  __shared__ uint4 Xb[16];  // 128 halfs: [0..64)=y-part, [64..128)=hist
  __shared__ uint4 Hb[16];  // L1 output h1
  __shared__ uint4 Gb[16];  // L2 output h2

  const int lane = threadIdx.x;
  const int c = lane & 15;
  const int kg = lane >> 4;
  const int kb = kg * 8;

  const float ts0 = gts[0];
  const float dt = gts[1] - gts[0];

  // ---- whole MLP -> VGPRs (one-time; rows LLC-resident across 512 blocks) ----
  half8 w1b[8][4], w2b[8][4], w3b[4][4];
  float b1t[8], w1tt[8], b2t[8];
#pragma unroll
  for (int t = 0; t < 8; ++t) {
    const int n = 16 * t + c;
#pragma unroll
    for (int ks = 0; ks < 4; ++ks) {
      const float* p1 = gW1 + n * 129 + ks * 32 + kb;
      const float* p2 = gW2 + n * 128 + ks * 32 + kb;
      half8 v1, v2;
#pragma unroll
      for (int e = 0; e < 8; ++e) { v1[e] = (_Float16)p1[e]; v2[e] = (_Float16)p2[e]; }
      w1b[t][ks] = v1; w2b[t][ks] = v2;
    }
    b1t[t] = gb1[n];
    w1tt[t] = gW1[n * 129 + 128];
    b2t[t] = gb2[n];
  }
#pragma unroll
  for (int t = 0; t < 4; ++t) {
    const int n = 16 * t + c;
#pragma unroll
    for (int ks = 0; ks < 4; ++ks) {
      const float* p3 = gW3 + n * 128 + ks * 32 + kb;
      half8 v3;
#pragma unroll
      for (int e = 0; e < 8; ++e) v3[e] = (_Float16)p3[e];
      w3b[t][ks] = v3;
    }
  }
  const float b3d = gb3[lane];  // = gb3[16*kg + c], matches the kg-select

  const size_t obt = (size_t)blockIdx.x * (NROW * D);
  const float* gme = gout + obt + lane;

  float y, y0v, yp0, yp1, np0 = 0.f, np1 = 0.f;
  float k1, k2, k3, k4, k5, k6;

  y0v = gy0[blockIdx.x * D + lane];
  y = y0v; yp0 = y0v; yp1 = y0v;
  gout[obt + lane] = y0v;                     // dense row 0 = y0
  {
    ushort_t* xp = (ushort_t*)Xb;
    xp[lane] = CVT16(y0v);                    // k1 input [y0 | y0]
    xp[D + lane] = CVT16(y0v);
  }
  if (blockIdx.x == 0 && lane == 0) gout[(size_t)BATCH * NROW * D] = 600.0f;  // num_steps
  cfence();

  const floatx4 zero4 = {0.f, 0.f, 0.f, 0.f};

  // 128-out layer: OUT = relu(W*IN + B + TV*TS). 8 independent acc chains.
#define L128(WB, BT, TV, TS, IN, OUT)                                         \
  {                                                                           \
    cfence();                                                                 \
    const half8* xp = (const half8*)(IN) + kg;                                \
    half8 a0 = xp[0], a1 = xp[4], a2 = xp[8], a3 = xp[12];                    \
    floatx4 q0, q1, q2, q3, q4, q5, q6, q7;                                   \
    q0 = mfma16(a0, WB[0][0], zero4); q1 = mfma16(a0, WB[1][0], zero4);       \
    q2 = mfma16(a0, WB[2][0], zero4); q3 = mfma16(a0, WB[3][0], zero4);       \
    q4 = mfma16(a0, WB[4][0], zero4); q5 = mfma16(a0, WB[5][0], zero4);       \
    q6 = mfma16(a0, WB[6][0], zero4); q7 = mfma16(a0, WB[7][0], zero4);       \
    q0 = mfma16(a1, WB[0][1], q0); q1 = mfma16(a1, WB[1][1], q1);             \
    q2 = mfma16(a1, WB[2][1], q2); q3 = mfma16(a1, WB[3][1], q3);             \
    q4 = mfma16(a1, WB[4][1], q4); q5 = mfma16(a1, WB[5][1], q5);             \
    q6 = mfma16(a1, WB[6][1], q6); q7 = mfma16(a1, WB[7][1], q7);             \
    q0 = mfma16(a2, WB[0][2], q0); q1 = mfma16(a2, WB[1][2], q1);             \
    q2 = mfma16(a2, WB[2][2], q2); q3 = mfma16(a2, WB[3][2], q3);             \
    q4 = mfma16(a2, WB[4][2], q4); q5 = mfma16(a2, WB[5][2], q5);             \
    q6 = mfma16(a2, WB[6][2], q6); q7 = mfma16(a2, WB[7][2], q7);             \
    q0 = mfma16(a3, WB[0][3], q0); q1 = mfma16(a3, WB[1][3], q1);             \
    q2 = mfma16(a3, WB[2][3], q2); q3 = mfma16(a3, WB[3][3], q3);             \
    q4 = mfma16(a3, WB[4][3], q4); q5 = mfma16(a3, WB[5][3], q5);             \
    q6 = mfma16(a3, WB[6][3], q6); q7 = mfma16(a3, WB[7][3], q7);             \
    if (lane < 16) {                                                          \
      ushort_t* op = (ushort_t*)(OUT);                                        \
      op[c]       = CVT16(fmaxf(q0[0] + fmaf(TV[0], (TS), BT[0]), 0.f));      \
      op[16 + c]  = CVT16(fmaxf(q1[0] + fmaf(TV[1], (TS), BT[1]), 0.f));      \
      op[32 + c]  = CVT16(fmaxf(q2[0] + fmaf(TV[2], (TS), BT[2]), 0.f));      \
      op[48 + c]  = CVT16(fmaxf(q3[0] + fmaf(TV[3], (TS), BT[3]), 0.f));      \
      op[64 + c]  = CVT16(fmaxf(q4[0] + fmaf(TV[4], (TS), BT[4]), 0.f));      \
      op[80 + c]  = CVT16(fmaxf(q5[0] + fmaf(TV[5], (TS), BT[5]), 0.f));      \
      op[96 + c]  = CVT16(fmaxf(q6[0] + fmaf(TV[6], (TS), BT[6]), 0.f));      \
      op[112 + c] = CVT16(fmaxf(q7[0] + fmaf(TV[7], (TS), BT[7]), 0.f));      \
    }                                                                         \
    cfence();                                                                 \
  }

  static const float ZV[8] = {0.f, 0.f, 0.f, 0.f, 0.f, 0.f, 0.f, 0.f};

  // MLP3: L1 Xb->Hb, L2 Hb->Gb, L3 Gb -> KS (valid in all lanes, elem=lane)
#define MLP3(TS)                                                              \
  L128(w1b, b1t, w1tt, (TS), Xb, Hb)                                          \
  L128(w2b, b2t, ZV, 0.f, Hb, Gb)                                             \
  {                                                                           \
    cfence();                                                                 \
    const half8* xp = (const half8*)Gb + kg;                                  \
    half8 g0 = xp[0], g1 = xp[4], g2 = xp[8], g3 = xp[12];                    \
    floatx4 r0, r1, r2, r3;                                                   \
    r0 = mfma16(g0, w3b[0][0], zero4); r1 = mfma16(g0, w3b[1][0], zero4);     \
    r2 = mfma16(g0, w3b[2][0], zero4); r3 = mfma16(g0, w3b[3][0], zero4);     \
    r0 = mfma16(g1, w3b[0][1], r0); r1 = mfma16(g1, w3b[1][1], r1);           \
    r2 = mfma16(g1, w3b[2][1], r2); r3 = mfma16(g1, w3b[3][1], r3);           \
    r0 = mfma16(g2, w3b[0][2], r0); r1 = mfma16(g2, w3b[1][2], r1);           \
    r2 = mfma16(g2, w3b[2][2], r2); r3 = mfma16(g2, w3b[3][2], r3);           \
    r0 = mfma16(g3, w3b[0][3], r0); r1 = mfma16(g3, w3b[1][3], r1);           \
    r2 = mfma16(g3, w3b[2][3], r2); r3 = mfma16(g3, w3b[3][3], r3);           \
    KS = ((kg == 0) ? r0[0] : (kg == 1) ? r1[0] : (kg == 2) ? r2[0] : r3[0])  \
         + b3d;                                                               \
    cfence();                                                                 \
  }

#define XWRITE(XV, HV)                          \
  {                                             \
    ushort_t* xp_ = (ushort_t*)Xb;              \
    xp_[lane] = CVT16(XV);                      \
    xp_[D + lane] = CVT16(HV);                  \
    cfence();                                   \
  }

  for (int n = 0; n < NSTEP; ++n) {
    const float tb = ts0 + (float)n * dt;
    float KS;

    // ---- history prefetch for step n+1 (consumed in stage-6 epilogue) ----
    {
      const int m = n + 1;
      const int r0 = (m >= SSEG) ? (m - SSEG) : 0;
      const int r1 = (m >= SSEG) ? (m - SSEG + 1) : 0;
      np0 = r0 ? gme[(size_t)r0 * D] : y0v;
      np1 = r1 ? gme[(size_t)r1 * D] : y0v;
    }

    // ---- stage 1: k1 ----
    MLP3(tb)
    k1 = KS;
    XWRITE(fmaf(dt, 0.2f * k1, y), fmaf(0.2f, yp1 - yp0, yp0))

    // ---- stage 2: k2 ----
    MLP3(tb + 0.2f * dt)
    k2 = KS;
    XWRITE(y + dt * ((3.f / 40.f) * k1 + (9.f / 40.f) * k2),
           fmaf(0.3f, yp1 - yp0, yp0))

    // ---- stage 3: k3 ----
    MLP3(tb + 0.3f * dt)
    k3 = KS;
    XWRITE(y + dt * ((44.f / 45.f) * k1 - (56.f / 15.f) * k2 + (32.f / 9.f) * k3),
           fmaf(0.8f, yp1 - yp0, yp0))

    // ---- stage 4: k4 ----
    MLP3(tb + 0.8f * dt)
    k4 = KS;
    XWRITE(y + dt * ((19372.f / 6561.f) * k1 - (25360.f / 2187.f) * k2 +
                     (64448.f / 6561.f) * k3 - (212.f / 729.f) * k4),
           fmaf(8.f / 9.f, yp1 - yp0, yp0))

    // ---- stage 5: k5 ----
    MLP3(tb + (8.f / 9.f) * dt)
    k5 = KS;
    XWRITE(y + dt * ((9017.f / 3168.f) * k1 - (355.f / 33.f) * k2 +
                     (46732.f / 5247.f) * k3 + (49.f / 176.f) * k4 -
                     (5103.f / 18656.f) * k5),
           yp1)  // k6 history is exactly yp1

    // ---- stage 6: k6 + y update + dense write + rotate history ----
    MLP3(tb + dt)
    k6 = KS;
    {
      float yn = y + dt * ((35.f / 384.f) * k1 + (500.f / 1113.f) * k3 +
                           (125.f / 192.f) * k4 - (2187.f / 6784.f) * k5 +
                           (11.f / 84.f) * k6);
      y = yn;
      gout[obt + (size_t)(n + 1) * D + lane] = yn;
      yp0 = np0;
      yp1 = np1;
      XWRITE(yn, yp0)  // next step's k1 input
    }
  }
#undef MLP3
#undef L128
#undef XWRITE
}

extern "C" void kernel_launch(void* const* d_in, const int* in_sizes, int n_in,
                              void* d_out, int out_size, void* d_ws, size_t ws_size,
                              hipStream_t stream) {
  const float* ts = (const float*)d_in[0];
  const float* y0 = (const float*)d_in[1];
  const float* W1 = (const float*)d_in[2];
  const float* b1 = (const float*)d_in[3];
  const float* W2 = (const float*)d_in[4];
  const float* b2 = (const float*)d_in[5];
  const float* W3 = (const float*)d_in[6];
  const float* b3 = (const float*)d_in[7];
  float* out = (float*)d_out;

  hipLaunchKernelGGL(NeuralDDEWithTime_46823733461186_kernel,
                     dim3(BATCH), dim3(64), 0, stream,
                     ts, y0, W1, b1, W2, b2, W3, b3, out);
}

// Round 7
// 2169.554 us; speedup vs baseline: 2.2322x; 2.2322x over previous
//
#include <hip/hip_runtime.h>

typedef _Float16 half8 __attribute__((ext_vector_type(8)));
typedef _Float16 h2f __attribute__((ext_vector_type(2)));
typedef float floatx4 __attribute__((ext_vector_type(4)));
typedef unsigned short ushort_t;
typedef unsigned int uint_t;

#define D 64
#define SSEG 120
#define NSTEP 600
#define NROW 601
#define BATCH 512
#define TPB 256
#define NBLK 256

static __device__ __forceinline__ uint_t pack2(float a, float b) {
  h2f v; v.x = (_Float16)a; v.y = (_Float16)b;
  return __builtin_bit_cast(uint_t, v);
}
static __device__ __forceinline__ floatx4 mfma16(half8 a, half8 b, floatx4 c) {
  return __builtin_amdgcn_mfma_f32_16x16x32_f16(a, b, c, 0, 0, 0);
}
// LDS-only barrier (R4/R5-proven): order LDS without draining vmcnt.
static __device__ __forceinline__ void bar_lds() {
  __builtin_amdgcn_sched_barrier(0);
  asm volatile("s_waitcnt lgkmcnt(0)" ::: "memory");
  __builtin_amdgcn_s_barrier();
  __builtin_amdgcn_sched_barrier(0);
}

// One block = TWO trajectories (M=2 in the MFMA A-operand). 256 blocks x 256
// threads -> exactly 1 block/CU. A-frag: lane c==0 rows <- trajA x, c==1 ->
// trajB, c>=2 dup trajA (harmless). C-layout (m89): col=lane&15, row=
// (lane>>4)*4+reg -> lanes<16 hold reg0=trajA, reg1=trajB. All LDS h/x
// buffers store PACKED u32 pairs; consumer weight k-columns are loaded
// pre-permuted to compensate (free at init):
//   Xb word d = (y_d, hist_d)            -> pi1(i) = 64*(i&1) + (i>>1)
//   Hb/Gb word 16w+c = (h[32w+c], h[32w+16+c])
//                                        -> pi2(i) = 32*(i>>5)+16*(i&1)+((i&31)>>1)
extern "C" __global__ void __launch_bounds__(TPB, 1)
NeuralDDEWithTime_46823733461186_kernel(
    const float* __restrict__ gts, const float* __restrict__ gy0,
    const float* __restrict__ gW1, const float* __restrict__ gb1,
    const float* __restrict__ gW2, const float* __restrict__ gb2,
    const float* __restrict__ gW3, const float* __restrict__ gb3,
    float* __restrict__ gout) {
  __shared__ half8 Xb[2][16];  // [traj][16 uint4-chunks] packed pairs
  __shared__ half8 Hb[2][16];
  __shared__ half8 Gb[2][16];

  const int tid = threadIdx.x;
  const int lane = tid & 63;
  const int w = tid >> 6;        // wave 0..3
  const int c = lane & 15;
  const int kg = lane >> 4;
  const bool wr = (lane < 16);
  const int d = 16 * w + c;      // this (wave,lane<16)'s state element

  const float ts0 = gts[0];
  const float dt = gts[1] - gts[0];

  // ---- weights -> VGPR B-frags with compensating column permutation ----
  half8 w1b[2][4], w2b[2][4], w3b[4];
  float b1t[2], w1tt[2], b2t[2];
#pragma unroll
  for (int t = 0; t < 2; ++t) {
    const int n = 32 * w + 16 * t + c;
#pragma unroll
    for (int ks = 0; ks < 4; ++ks) {
      half8 v1, v2;
#pragma unroll
      for (int e = 0; e < 8; ++e) {
        const int s = 32 * ks + 8 * kg + e;                       // A k-slot
        const int p1 = 64 * (s & 1) + (s >> 1);                   // Xb layout
        const int p2 = 32 * (s >> 5) + 16 * (s & 1) + ((s & 31) >> 1);  // Hb/Gb
        v1[e] = (_Float16)gW1[n * 129 + p1];
        v2[e] = (_Float16)gW2[n * 128 + p2];
      }
      w1b[t][ks] = v1;
      w2b[t][ks] = v2;
    }
    b1t[t] = gb1[n];
    w1tt[t] = gW1[n * 129 + 128];
    b2t[t] = gb2[n];
  }
#pragma unroll
  for (int ks = 0; ks < 4; ++ks) {
    const int n = 16 * w + c;
    half8 v3;
#pragma unroll
    for (int e = 0; e < 8; ++e) {
      const int s = 32 * ks + 8 * kg + e;
      const int p2 = 32 * (s >> 5) + 16 * (s & 1) + ((s & 31) >> 1);
      v3[e] = (_Float16)gW3[n * 128 + p2];
    }
    w3b[ks] = v3;
  }
  const float b3r = gb3[16 * w + c];

  const int bA = blockIdx.x * 2, bB = bA + 1;
  const size_t oA = (size_t)bA * (NROW * D);
  const size_t oB = (size_t)bB * (NROW * D);
  const float* gmeA = gout + oA + d;
  const float* gmeB = gout + oB + d;

  const float y0A = gy0[bA * D + d], y0B = gy0[bB * D + d];
  float yA = y0A, yB = y0B;
  float ypA0 = y0A, ypA1 = y0A, ypB0 = y0B, ypB1 = y0B;
  float npA0 = 0.f, npA1 = 0.f, npB0 = 0.f, npB1 = 0.f;
  float k1A, k2A, k3A, k4A, k5A, k6A;
  float k1B, k2B, k3B, k4B, k5B, k6B;

  if (wr) {
    gout[oA + d] = y0A;                       // dense row 0 = y0
    gout[oB + d] = y0B;
    uint_t* xw = (uint_t*)Xb;
    xw[d] = pack2(y0A, y0A);                  // k1 input word = (y, hist)
    xw[64 + d] = pack2(y0B, y0B);
  }
  if (blockIdx.x == 0 && tid == 0) gout[(size_t)BATCH * NROW * D] = 600.0f;  // num_steps
  bar_lds();

  const floatx4 zero4 = {0.f, 0.f, 0.f, 0.f};
  static const float ZV2[2] = {0.f, 0.f};

  // 128-out layer, both trajectories: depth-2 MFMA chains + packed u32 write.
#define L128(WB, BB, TVV, TS, IN, OUT)                                        \
  {                                                                           \
    const half8* xp = (const half8*)(IN) + ((c == 1) << 4) + kg;              \
    half8 a0 = xp[0], a1 = xp[4], a2 = xp[8], a3 = xp[12];                    \
    __builtin_amdgcn_s_setprio(1);                                            \
    floatx4 qA0 = mfma16(a0, WB[0][0], zero4);                                \
    floatx4 qB0 = mfma16(a0, WB[1][0], zero4);                                \
    floatx4 qA1 = mfma16(a2, WB[0][2], zero4);                                \
    floatx4 qB1 = mfma16(a2, WB[1][2], zero4);                                \
    qA0 = mfma16(a1, WB[0][1], qA0); qB0 = mfma16(a1, WB[1][1], qB0);         \
    qA1 = mfma16(a3, WB[0][3], qA1); qB1 = mfma16(a3, WB[1][3], qB1);         \
    __builtin_amdgcn_s_setprio(0);                                            \
    const float bA_ = fmaf((TVV)[0], (TS), (BB)[0]);                          \
    const float bB_ = fmaf((TVV)[1], (TS), (BB)[1]);                          \
    const float hA0 = fmaxf(qA0[0] + qA1[0] + bA_, 0.f);                      \
    const float hB0 = fmaxf(qB0[0] + qB1[0] + bB_, 0.f);                      \
    const float hA1 = fmaxf(qA0[1] + qA1[1] + bA_, 0.f);                      \
    const float hB1 = fmaxf(qB0[1] + qB1[1] + bB_, 0.f);                      \
    if (wr) {                                                                 \
      uint_t* op = (uint_t*)(OUT);                                            \
      op[d] = pack2(hA0, hB0);                                                \
      op[64 + d] = pack2(hA1, hB1);                                           \
    }                                                                         \
  }

  // MLP3: L1 Xb->Hb, L2 Hb->Gb, L3 Gb -> (KSA, KSB) valid in lanes<16.
#define MLP3(TS)                                                              \
  L128(w1b, b1t, w1tt, (TS), Xb, Hb)                                          \
  bar_lds();                                                                  \
  L128(w2b, b2t, ZV2, 0.f, Hb, Gb)                                            \
  bar_lds();                                                                  \
  {                                                                           \
    const half8* xp = (const half8*)(Gb) + ((c == 1) << 4) + kg;              \
    half8 g0 = xp[0], g1 = xp[4], g2 = xp[8], g3 = xp[12];                    \
    __builtin_amdgcn_s_setprio(1);                                            \
    floatx4 r0 = mfma16(g0, w3b[0], zero4);                                   \
    floatx4 r1 = mfma16(g2, w3b[2], zero4);                                   \
    r0 = mfma16(g1, w3b[1], r0);                                              \
    r1 = mfma16(g3, w3b[3], r1);                                              \
    __builtin_amdgcn_s_setprio(0);                                            \
    KSA = r0[0] + r1[0] + b3r;                                                \
    KSB = r0[1] + r1[1] + b3r;                                                \
  }

#define XWRITE(XVA, HVA, XVB, HVB)             \
  if (wr) {                                    \
    uint_t* xw = (uint_t*)Xb;                  \
    xw[d] = pack2((XVA), (HVA));               \
    xw[64 + d] = pack2((XVB), (HVB));          \
  }

  for (int n = 0; n < NSTEP; ++n) {
    const float tb = ts0 + (float)n * dt;
    float KSA, KSB;

    // ---- history prefetch for step n+1 (consumed in stage-6 epilogue) ----
    {
      const int m = n + 1;
      const int r0 = (m >= SSEG) ? (m - SSEG) : 0;
      const int r1 = (m >= SSEG) ? (m - SSEG + 1) : 0;
      npA0 = r0 ? gmeA[(size_t)r0 * D] : y0A;
      npA1 = r1 ? gmeA[(size_t)r1 * D] : y0A;
      npB0 = r0 ? gmeB[(size_t)r0 * D] : y0B;
      npB1 = r1 ? gmeB[(size_t)r1 * D] : y0B;
    }

    // ---- stage 1: k1 ----
    MLP3(tb)
    k1A = KSA; k1B = KSB;
    XWRITE(fmaf(dt, 0.2f * k1A, yA), fmaf(0.2f, ypA1 - ypA0, ypA0),
           fmaf(dt, 0.2f * k1B, yB), fmaf(0.2f, ypB1 - ypB0, ypB0))
    bar_lds();

    // ---- stage 2: k2 ----
    MLP3(tb + 0.2f * dt)
    k2A = KSA; k2B = KSB;
    XWRITE(yA + dt * ((3.f / 40.f) * k1A + (9.f / 40.f) * k2A),
           fmaf(0.3f, ypA1 - ypA0, ypA0),
           yB + dt * ((3.f / 40.f) * k1B + (9.f / 40.f) * k2B),
           fmaf(0.3f, ypB1 - ypB0, ypB0))
    bar_lds();

    // ---- stage 3: k3 ----
    MLP3(tb + 0.3f * dt)
    k3A = KSA; k3B = KSB;
    XWRITE(yA + dt * ((44.f / 45.f) * k1A - (56.f / 15.f) * k2A + (32.f / 9.f) * k3A),
           fmaf(0.8f, ypA1 - ypA0, ypA0),
           yB + dt * ((44.f / 45.f) * k1B - (56.f / 15.f) * k2B + (32.f / 9.f) * k3B),
           fmaf(0.8f, ypB1 - ypB0, ypB0))
    bar_lds();

    // ---- stage 4: k4 ----
    MLP3(tb + 0.8f * dt)
    k4A = KSA; k4B = KSB;
    XWRITE(yA + dt * ((19372.f / 6561.f) * k1A - (25360.f / 2187.f) * k2A +
                      (64448.f / 6561.f) * k3A - (212.f / 729.f) * k4A),
           fmaf(8.f / 9.f, ypA1 - ypA0, ypA0),
           yB + dt * ((19372.f / 6561.f) * k1B - (25360.f / 2187.f) * k2B +
                      (64448.f / 6561.f) * k3B - (212.f / 729.f) * k4B),
           fmaf(8.f / 9.f, ypB1 - ypB0, ypB0))
    bar_lds();

    // ---- stage 5: k5 ----
    MLP3(tb + (8.f / 9.f) * dt)
    k5A = KSA; k5B = KSB;
    XWRITE(yA + dt * ((9017.f / 3168.f) * k1A - (355.f / 33.f) * k2A +
                      (46732.f / 5247.f) * k3A + (49.f / 176.f) * k4A -
                      (5103.f / 18656.f) * k5A),
           ypA1,  // k6 history is exactly yp1
           yB + dt * ((9017.f / 3168.f) * k1B - (355.f / 33.f) * k2B +
                      (46732.f / 5247.f) * k3B + (49.f / 176.f) * k4B -
                      (5103.f / 18656.f) * k5B),
           ypB1)
    bar_lds();

    // ---- stage 6: k6 + y update + dense write + rotate history ----
    MLP3(tb + dt)
    k6A = KSA; k6B = KSB;
    {
      const float ynA = yA + dt * ((35.f / 384.f) * k1A + (500.f / 1113.f) * k3A +
                                   (125.f / 192.f) * k4A - (2187.f / 6784.f) * k5A +
                                   (11.f / 84.f) * k6A);
      const float ynB = yB + dt * ((35.f / 384.f) * k1B + (500.f / 1113.f) * k3B +
                                   (125.f / 192.f) * k4B - (2187.f / 6784.f) * k5B +
                                   (11.f / 84.f) * k6B);
      yA = ynA; yB = ynB;
      if (wr) {
        gout[oA + (size_t)(n + 1) * D + d] = ynA;
        gout[oB + (size_t)(n + 1) * D + d] = ynB;
      }
      ypA0 = npA0; ypA1 = npA1;
      ypB0 = npB0; ypB1 = npB1;
      XWRITE(ynA, ypA0, ynB, ypB0)  // next step's k1 input
    }
    bar_lds();
  }
#undef MLP3
#undef L128
#undef XWRITE
}

extern "C" void kernel_launch(void* const* d_in, const int* in_sizes, int n_in,
                              void* d_out, int out_size, void* d_ws, size_t ws_size,
                              hipStream_t stream) {
  const float* ts = (const float*)d_in[0];
  const float* y0 = (const float*)d_in[1];
  const float* W1 = (const float*)d_in[2];
  const float* b1 = (const float*)d_in[3];
  const float* W2 = (const float*)d_in[4];
  const float* b2 = (const float*)d_in[5];
  const float* W3 = (const float*)d_in[6];
  const float* b3 = (const float*)d_in[7];
  float* out = (float*)d_out;

  hipLaunchKernelGGL(NeuralDDEWithTime_46823733461186_kernel,
                     dim3(NBLK), dim3(TPB), 0, stream,
                     ts, y0, W1, b1, W2, b2, W3, b3, out);
}